// Round 10
// baseline (102.379 us; speedup 1.0000x reference)
//
#include <hip/hip_runtime.h>

// Problem constants: B=1024, F=33, D=128, A=128, P=F*(F-1)/2=528
#define FN 33
#define DN 128
#define AN 128
#define PN 528
#define XS 136     // fp16 row stride for xh in LDS (272 B, 16B-aligned, non-pow2)
#define TS 36      // float row stride for attn2d (144 B)

typedef __attribute__((ext_vector_type(8))) _Float16 half8;
typedef __attribute__((ext_vector_type(4))) float f32x4;
typedef __attribute__((ext_vector_type(4))) unsigned int u32x4;

__device__ __forceinline__ unsigned int pkrtz(float a, float b) {
  return __builtin_bit_cast(unsigned int, __builtin_amdgcn_cvt_pkrtz(a, b));
}

// max over the 16-lane DPP row via row_ror rotations (VALU pipe)
__device__ __forceinline__ float row_max16(float v) {
  v = fmaxf(v, __builtin_bit_cast(float, __builtin_amdgcn_update_dpp(0, __builtin_bit_cast(int, v), 0x128, 0xF, 0xF, false)));
  v = fmaxf(v, __builtin_bit_cast(float, __builtin_amdgcn_update_dpp(0, __builtin_bit_cast(int, v), 0x124, 0xF, 0xF, false)));
  v = fmaxf(v, __builtin_bit_cast(float, __builtin_amdgcn_update_dpp(0, __builtin_bit_cast(int, v), 0x122, 0xF, 0xF, false)));
  v = fmaxf(v, __builtin_bit_cast(float, __builtin_amdgcn_update_dpp(0, __builtin_bit_cast(int, v), 0x121, 0xF, 0xF, false)));
  return v;
}

// ---- staging: issue x loads early (pinned), convert+store later ------------
#define XLOAD(XV, XT, BB)                                                     \
  {                                                                           \
    const f32x4* xb = (const f32x4*)(xg + (size_t)(BB) * FN * DN);            \
    _Pragma("unroll")                                                         \
    for (int s = 0; s < 4; s++) {                                             \
      XV[s] = xb[tid + s * 256];                                              \
      asm volatile("" : "+v"(XV[s]));                                         \
    }                                                                         \
    if (tid < 32) XT = xb[1024 + tid];                                        \
    asm volatile("" : "+v"(XT));                                              \
  }

#define XSTORE(XV, XT, BUFI)                                                  \
  {                                                                           \
    _Pragma("unroll")                                                         \
    for (int s = 0; s < 4; s++) {                                             \
      const int idx = tid + s * 256;                                          \
      const int i = idx >> 5, d0 = (idx & 31) << 2;                           \
      *(uint2*)&xh[BUFI][i * XS + d0] =                                       \
          make_uint2(pkrtz(XV[s].x, XV[s].y), pkrtz(XV[s].z, XV[s].w));       \
    }                                                                         \
    if (tid < 32) {                                                           \
      const int idx = 1024 + tid;                                             \
      const int i = idx >> 5, d0 = (idx & 31) << 2;                           \
      *(uint2*)&xh[BUFI][i * XS + d0] =                                       \
          make_uint2(pkrtz(XT.x, XT.y), pkrtz(XT.z, XT.w));                   \
    }                                                                         \
  }

// lane-local relu-dot, VECTOR form: elementwise max + packed-f32 fma on the
// naturally-aligned f32x4 acc/gnn quads (v_pk_fma_f32: halves the fma count),
// two independent chains for ILP, 3-add horizontal at the end.
#define RELUDOT(ACC, GQ, DST)                                                 \
  {                                                                           \
    const f32x4 z4 = (f32x4){0.f, 0.f, 0.f, 0.f};                             \
    f32x4 sva = __builtin_elementwise_fma(                                    \
        __builtin_elementwise_max(ACC[0], z4), GQ[0], z4);                    \
    f32x4 svb = __builtin_elementwise_fma(                                    \
        __builtin_elementwise_max(ACC[1], z4), GQ[1], z4);                    \
    sva = __builtin_elementwise_fma(                                          \
        __builtin_elementwise_max(ACC[2], z4), GQ[2], sva);                   \
    svb = __builtin_elementwise_fma(                                          \
        __builtin_elementwise_max(ACC[3], z4), GQ[3], svb);                   \
    f32x4 sv = sva + svb;                                                     \
    DST = (sv.x + sv.y) + (sv.z + sv.w);                                      \
  }

// ---- S: exp with upper-bound shift M^ = sum over 4 groups of
// max-over-mh(group max). Uniform shift >= true max: softmax ratio exact
// (validated R5-R9); overshoot e^-delta fp32-safe.
#define SPH(PARM)                                                             \
  {                                                                           \
    const float Mh =                                                          \
        (fmaxf(rmax[PARM][0], rmax[PARM][4]) +                                \
         fmaxf(rmax[PARM][1], rmax[PARM][5])) +                               \
        (fmaxf(rmax[PARM][2], rmax[PARM][6]) +                                \
         fmaxf(rmax[PARM][3], rmax[PARM][7]));                                \
    float s0 = (sp[PARM][0][tid] + sp[PARM][1][tid]) +                        \
               (sp[PARM][2][tid] + sp[PARM][3][tid]);                         \
    float s1 = (sp[PARM][0][tid + 256] + sp[PARM][1][tid + 256]) +            \
               (sp[PARM][2][tid + 256] + sp[PARM][3][tid + 256]);             \
    float e0 = __expf(s0 - Mh);                                               \
    float e1 = __expf(s1 - Mh);                                               \
    unsigned int rc = rowcol[tid];                                            \
    attn2d[PARM][(rc & 255) * TS + ((rc >> 8) - (rc & 255) - 1)] = e0;        \
    rc = rowcol[tid + 256];                                                   \
    attn2d[PARM][(rc & 255) * TS + ((rc >> 8) - (rc & 255) - 1)] = e1;        \
    float e2 = 0.f;                                                           \
    if (tid < 16) {                                                           \
      float s2 = (sp[PARM][0][tid + 512] + sp[PARM][1][tid + 512]) +          \
                 (sp[PARM][2][tid + 512] + sp[PARM][3][tid + 512]);           \
      e2 = __expf(s2 - Mh);                                                   \
      rc = rowcol[tid + 512];                                                 \
      attn2d[PARM][(rc & 255) * TS + ((rc >> 8) - (rc & 255) - 1)] = e2;      \
    }                                                                         \
    float ls = (e0 + e1) + e2;                                                \
    _Pragma("unroll")                                                         \
    for (int off = 32; off >= 1; off >>= 1) ls += __shfl_xor(ls, off, 64);    \
    if (lane == 0) rsum[PARM][wave] = ls;                                     \
  }

// R10: R9 + (a) vector RELUDOT (v_pk_fma_f32, ~16 fewer VALU/tile) and
// (b) EPI xcol loads hoisted into phase 2 (xh stable since B1; only attn2d
// reads need B3) so their LDS latency hides under SPH.  Schedule unchanged:
// 3 barriers per 2 batches.
__global__ __launch_bounds__(256, 2)
void afm_kernel(const float* __restrict__ gnn, const float* __restrict__ xg,
                const float* __restrict__ Wg,  const float* __restrict__ bg,
                float* __restrict__ out)
{
  __shared__ __align__(16) _Float16 xh[2][FN * XS];     // 17.9 KB
  __shared__ __align__(16) float attn2d[2][FN * TS];    // 9.5 KB
  __shared__ __align__(16) float sp[2][4][PN];          // 16.9 KB [bi][group][p]
  __shared__ unsigned short rowcol[PN];                 // 1 KB
  __shared__ float rmax[2][8], rsum[2][4];

  const int tid  = threadIdx.x;
  const int b0   = blockIdx.x * 2;
  const int b1   = b0 + 1;
  const int wave = tid >> 6;
  const int lane = tid & 63;
  const int q    = lane >> 4;   // quad 0..3
  const int u    = lane & 15;
  const int nh   = wave & 1;    // n-half: cols [nh*64, nh*64+64)
  const int mh   = wave >> 1;   // m-half: tiles [0,17) / [17,33)

  // -------- x loads for BOTH batches issued first ---------------------------
  f32x4 xv0[4], xv1[4];
  f32x4 xt0 = {0,0,0,0}, xt1 = {0,0,0,0};
  XLOAD(xv0, xt0, b0);
  XLOAD(xv1, xt1, b1);

  // gnn passthrough value for EPIBOTH (thread (bi,d) = (tid>>7, tid&127))
  const float gpass = gnn[(size_t)(b0 + (tid >> 7)) * AN + (tid & 127)];

  // -------- W quadrant -> Bf regs; per-lane bias/gnn vectors ----------------
  // Bf[nn][kk]: lane holds W[a = nh*64+nn*16+u][k = kk*32+q*8 .. +8]
  // bq/gq[nn]: lane holds {bias,gnn}[a = nh*64+nn*16+q*4 .. +4] (fm^T layout)
  half8 Bf[4][4];
  f32x4 bq[4], g0q[4], g1q[4];
  #pragma unroll
  for (int nn = 0; nn < 4; nn++) {
    const int a = nh * 64 + nn * 16 + u;
    const float* src = Wg + (size_t)a * DN + q * 8;
    #pragma unroll
    for (int kk = 0; kk < 4; kk++) {
      f32x4 w0 = *(const f32x4*)(src + kk * 32);
      f32x4 w1 = *(const f32x4*)(src + kk * 32 + 4);
      u32x4 pk;
      pk.x = pkrtz(w0.x, w0.y);
      pk.y = pkrtz(w0.z, w0.w);
      pk.z = pkrtz(w1.x, w1.y);
      pk.w = pkrtz(w1.z, w1.w);
      Bf[nn][kk] = __builtin_bit_cast(half8, pk);
      asm volatile("" : "+v"(Bf[nn][kk]));   // pin: forbid remat/sinking
    }
    const int abase = nh * 64 + nn * 16 + q * 4;
    bq[nn]  = *(const f32x4*)&bg[abase];
    g0q[nn] = *(const f32x4*)&gnn[(size_t)b0 * AN + abase];
    g1q[nn] = *(const f32x4*)&gnn[(size_t)b1 * AN + abase];
    asm volatile("" : "+v"(bq[nn]), "+v"(g0q[nn]), "+v"(g1q[nn]));
  }

  // -------- VALU-only staging overlapped with load flight -------------------
  {
    float* a2z = &attn2d[0][0];
    for (int idx = tid; idx < 2 * FN * TS; idx += 256) a2z[idx] = 0.0f;
    for (int p = tid; p < PN; p += 256) {
      int i = 0, rem = p;
      while (rem >= FN - 1 - i) { rem -= FN - 1 - i; i++; }
      rowcol[p] = (unsigned short)(i | ((i + 1 + rem) << 8));
    }
  }
  XSTORE(xv0, xt0, 0);
  XSTORE(xv1, xt1, 1);
  __syncthreads();                                      // B1

  // -------- phase 1: interleaved walk over b0 AND b1 ------------------------
  {
    const int t_beg = mh ? 17 : 0;
    const int t_end = mh ? 33 : 17;
    float wm0 = -3.4e38f, wm1 = -3.4e38f;
    unsigned int rc_next = rowcol[t_beg * 16 + u];
    for (int t = t_beg; t < t_end; ++t) {
      const unsigned int rc = rc_next;
      if (t + 1 < t_end) rc_next = rowcol[(t + 1) * 16 + u];
      const int off_r = (rc & 255) * XS + q * 8;     // shared by both batches
      const int off_c = (rc >> 8) * XS + q * 8;

      f32x4 a0[4], a1[4];
      #pragma unroll
      for (int nn = 0; nn < 4; nn++) { a0[nn] = bq[nn]; a1[nn] = bq[nn]; }

      __builtin_amdgcn_s_setprio(1);
      #pragma unroll
      for (int kk = 0; kk < 4; kk++) {
        half8 af0 = *(const half8*)&xh[0][off_r + kk * 32] *
                    *(const half8*)&xh[0][off_c + kk * 32];
        half8 af1 = *(const half8*)&xh[1][off_r + kk * 32] *
                    *(const half8*)&xh[1][off_c + kk * 32];
        #pragma unroll
        for (int nn = 0; nn < 4; nn++) {
          a0[nn] = __builtin_amdgcn_mfma_f32_16x16x32_f16(Bf[nn][kk], af0, a0[nn], 0, 0, 0);
          a1[nn] = __builtin_amdgcn_mfma_f32_16x16x32_f16(Bf[nn][kk], af1, a1[nn], 0, 0, 0);
        }
      }
      __builtin_amdgcn_s_setprio(0);

      float s0, s1;
      RELUDOT(a0, g0q, s0);
      RELUDOT(a1, g1q, s1);
      s0 += __shfl_xor(s0, 16, 64);      // two independent bperms: pipelined
      s1 += __shfl_xor(s1, 16, 64);
      wm0 = fmaxf(wm0, s0);
      wm1 = fmaxf(wm1, s1);
      if ((q & 1) == 0) {
        const int gidx = (nh * 2 + (q >> 1)) * PN + t * 16 + u;
        (&sp[0][0][0])[gidx] = s0;
        (&sp[1][0][0])[gidx] = s1;
      }
    }
    wm0 = row_max16(wm0);
    wm1 = row_max16(wm1);
    if (lane == 0)  { rmax[0][wave * 2]     = wm0; rmax[1][wave * 2]     = wm1; }
    if (lane == 32) { rmax[0][wave * 2 + 1] = wm0; rmax[1][wave * 2 + 1] = wm1; }
  }
  __syncthreads();                                      // B2

  // -------- phase 2: xcol prefetch (overlaps SPH) + SPH(b0) + SPH(b1) -------
  const int bi = tid >> 7;          // wave-uniform (waves 0,1 -> b0; 2,3 -> b1)
  const int d  = tid & 127;
  float xcol[36];
  {
    const _Float16* xhb = &xh[bi][0];
    #pragma unroll
    for (int i = 0; i < FN; i++) xcol[i] = (float)xhb[i * XS + d];
    xcol[33] = 0.f; xcol[34] = 0.f; xcol[35] = 0.f;
  }
  SPH(0);
  SPH(1);
  __syncthreads();                                      // B3

  // -------- phase 3: EPIBOTH — thread (bi,d) computes batch bi, col d -------
  {
    const float* a2 = &attn2d[bi][0];
    const float Zb = (rsum[bi][0] + rsum[bi][1]) + (rsum[bi][2] + rsum[bi][3]);

    float acc0 = 0.f, acc1 = 0.f;     // i-parity split accumulators (ILP)
    #pragma unroll
    for (int i = 0; i < 32; i++) {
      const int L = FN - 1 - i;                  // pairs (i, i+1+jj), jj < L
      const int nf4 = (L + 3) >> 2;
      float ti = 0.f;
      #pragma unroll
      for (int t = 0; t < nf4; t++) {
        f32x4 a4 = *(const f32x4*)&a2[i * TS + t * 4];  // pad entries are 0
        ti = fmaf(a4.x, xcol[i + 1 + t * 4 + 0], ti);
        ti = fmaf(a4.y, xcol[i + 1 + t * 4 + 1], ti);
        ti = fmaf(a4.z, xcol[i + 1 + t * 4 + 2], ti);
        ti = fmaf(a4.w, xcol[i + 1 + t * 4 + 3], ti);
      }
      if (i & 1) acc1 = fmaf(xcol[i], ti, acc1);
      else       acc0 = fmaf(xcol[i], ti, acc0);
    }
    const size_t obase = (size_t)(b0 + bi) * (AN + DN);
    out[obase + AN + d] = (acc0 + acc1) * (100.0f / Zb);
    out[obase + d] = gpass;
  }
}

extern "C" void kernel_launch(void* const* d_in, const int* in_sizes, int n_in,
                              void* d_out, int out_size, void* d_ws, size_t ws_size,
                              hipStream_t stream) {
  (void)n_in; (void)out_size; (void)d_ws; (void)ws_size;
  const float* gnn  = (const float*)d_in[0];
  const float* x    = (const float*)d_in[1];
  const float* W    = (const float*)d_in[2];
  const float* bias = (const float*)d_in[3];
  float* out = (float*)d_out;
  const int Bn = in_sizes[0] / AN;   // 1024
  afm_kernel<<<dim3(Bn / 2), dim3(256), 0, stream>>>(gnn, x, W, bias, out);
}

// Round 11
// 101.673 us; speedup vs baseline: 1.0069x; 1.0069x over previous
//
#include <hip/hip_runtime.h>

// Problem constants: B=1024, F=33, D=128, A=128, P=F*(F-1)/2=528
#define FN 33
#define DN 128
#define AN 128
#define PN 528
#define XS 136     // fp16 row stride for xh in LDS (272 B, 16B-aligned, non-pow2)
#define TS 36      // float row stride for attn2d (144 B)

typedef __attribute__((ext_vector_type(8))) _Float16 half8;
typedef __attribute__((ext_vector_type(4))) float f32x4;
typedef __attribute__((ext_vector_type(4))) unsigned int u32x4;

__device__ __forceinline__ unsigned int pkrtz(float a, float b) {
  return __builtin_bit_cast(unsigned int, __builtin_amdgcn_cvt_pkrtz(a, b));
}

// max over the 16-lane DPP row via row_ror rotations (VALU pipe)
__device__ __forceinline__ float row_max16(float v) {
  v = fmaxf(v, __builtin_bit_cast(float, __builtin_amdgcn_update_dpp(0, __builtin_bit_cast(int, v), 0x128, 0xF, 0xF, false)));
  v = fmaxf(v, __builtin_bit_cast(float, __builtin_amdgcn_update_dpp(0, __builtin_bit_cast(int, v), 0x124, 0xF, 0xF, false)));
  v = fmaxf(v, __builtin_bit_cast(float, __builtin_amdgcn_update_dpp(0, __builtin_bit_cast(int, v), 0x122, 0xF, 0xF, false)));
  v = fmaxf(v, __builtin_bit_cast(float, __builtin_amdgcn_update_dpp(0, __builtin_bit_cast(int, v), 0x121, 0xF, 0xF, false)));
  return v;
}

// ---- staging: issue x loads early (pinned), convert+store later ------------
#define XLOAD(XV, XT, BB)                                                     \
  {                                                                           \
    const f32x4* xb = (const f32x4*)(xg + (size_t)(BB) * FN * DN);            \
    _Pragma("unroll")                                                         \
    for (int s = 0; s < 4; s++) {                                             \
      XV[s] = xb[tid + s * 256];                                              \
      asm volatile("" : "+v"(XV[s]));                                         \
    }                                                                         \
    if (tid < 32) XT = xb[1024 + tid];                                        \
    asm volatile("" : "+v"(XT));                                              \
  }

#define XSTORE(XV, XT, BUFI)                                                  \
  {                                                                           \
    _Pragma("unroll")                                                         \
    for (int s = 0; s < 4; s++) {                                             \
      const int idx = tid + s * 256;                                          \
      const int i = idx >> 5, d0 = (idx & 31) << 2;                           \
      *(uint2*)&xh[BUFI][i * XS + d0] =                                       \
          make_uint2(pkrtz(XV[s].x, XV[s].y), pkrtz(XV[s].z, XV[s].w));       \
    }                                                                         \
    if (tid < 32) {                                                           \
      const int idx = 1024 + tid;                                             \
      const int i = idx >> 5, d0 = (idx & 31) << 2;                           \
      *(uint2*)&xh[BUFI][i * XS + d0] =                                       \
          make_uint2(pkrtz(XT.x, XT.y), pkrtz(XT.z, XT.w));                   \
    }                                                                         \
  }

// lane-local relu-dot of one fm^T accumulator set against gnn quads
// (all indices compile-time after inlining; 4 independent FMA chains)
// [R10 A/B: scalar form >= vector __builtin_elementwise form — kept scalar]
#define RELUDOT(ACC, GQ, DST)                                                 \
  {                                                                           \
    float sa0 = 0.f, sa1 = 0.f, sa2 = 0.f, sa3 = 0.f;                         \
    sa0 = fmaf(fmaxf(ACC[0][0], 0.f), GQ[0].x, sa0);                          \
    sa0 = fmaf(fmaxf(ACC[0][1], 0.f), GQ[0].y, sa0);                          \
    sa0 = fmaf(fmaxf(ACC[0][2], 0.f), GQ[0].z, sa0);                          \
    sa0 = fmaf(fmaxf(ACC[0][3], 0.f), GQ[0].w, sa0);                          \
    sa1 = fmaf(fmaxf(ACC[1][0], 0.f), GQ[1].x, sa1);                          \
    sa1 = fmaf(fmaxf(ACC[1][1], 0.f), GQ[1].y, sa1);                          \
    sa1 = fmaf(fmaxf(ACC[1][2], 0.f), GQ[1].z, sa1);                          \
    sa1 = fmaf(fmaxf(ACC[1][3], 0.f), GQ[1].w, sa1);                          \
    sa2 = fmaf(fmaxf(ACC[2][0], 0.f), GQ[2].x, sa2);                          \
    sa2 = fmaf(fmaxf(ACC[2][1], 0.f), GQ[2].y, sa2);                          \
    sa2 = fmaf(fmaxf(ACC[2][2], 0.f), GQ[2].z, sa2);                          \
    sa2 = fmaf(fmaxf(ACC[2][3], 0.f), GQ[2].w, sa2);                          \
    sa3 = fmaf(fmaxf(ACC[3][0], 0.f), GQ[3].x, sa3);                          \
    sa3 = fmaf(fmaxf(ACC[3][1], 0.f), GQ[3].y, sa3);                          \
    sa3 = fmaf(fmaxf(ACC[3][2], 0.f), GQ[3].z, sa3);                          \
    sa3 = fmaf(fmaxf(ACC[3][3], 0.f), GQ[3].w, sa3);                          \
    DST = (sa0 + sa1) + (sa2 + sa3);                                          \
  }

// ---- S: exp with upper-bound shift M^ = sum over 4 groups of
// max-over-mh(group max). Uniform shift >= true max: softmax ratio exact
// (validated R5-R9); overshoot e^-delta fp32-safe.
#define SPH(PARM)                                                             \
  {                                                                           \
    const float Mh =                                                          \
        (fmaxf(rmax[PARM][0], rmax[PARM][4]) +                                \
         fmaxf(rmax[PARM][1], rmax[PARM][5])) +                               \
        (fmaxf(rmax[PARM][2], rmax[PARM][6]) +                                \
         fmaxf(rmax[PARM][3], rmax[PARM][7]));                                \
    float s0 = (sp[PARM][0][tid] + sp[PARM][1][tid]) +                        \
               (sp[PARM][2][tid] + sp[PARM][3][tid]);                         \
    float s1 = (sp[PARM][0][tid + 256] + sp[PARM][1][tid + 256]) +            \
               (sp[PARM][2][tid + 256] + sp[PARM][3][tid + 256]);             \
    float e0 = __expf(s0 - Mh);                                               \
    float e1 = __expf(s1 - Mh);                                               \
    unsigned int rc = rowcol[tid];                                            \
    attn2d[PARM][(rc & 255) * TS + ((rc >> 8) - (rc & 255) - 1)] = e0;        \
    rc = rowcol[tid + 256];                                                   \
    attn2d[PARM][(rc & 255) * TS + ((rc >> 8) - (rc & 255) - 1)] = e1;        \
    float e2 = 0.f;                                                           \
    if (tid < 16) {                                                           \
      float s2 = (sp[PARM][0][tid + 512] + sp[PARM][1][tid + 512]) +          \
                 (sp[PARM][2][tid + 512] + sp[PARM][3][tid + 512]);           \
      e2 = __expf(s2 - Mh);                                                   \
      rc = rowcol[tid + 512];                                                 \
      attn2d[PARM][(rc & 255) * TS + ((rc >> 8) - (rc & 255) - 1)] = e2;      \
    }                                                                         \
    float ls = (e0 + e1) + e2;                                                \
    _Pragma("unroll")                                                         \
    for (int off = 32; off >= 1; off >>= 1) ls += __shfl_xor(ls, off, 64);    \
    if (lane == 0) rsum[PARM][wave] = ls;                                     \
  }

// R11 = R9 verbatim (session-best score 100.8 us): single interleaved walk
// over both batches (shared rowcol/address calc, 8 indep MFMA chains/tile,
// 2 pipelined shfl_xor), SPH(0)+SPH(1) in one phase, direct-write EPIBOTH.
// 3 barriers per 2 batches.  R10's two deltas (vector RELUDOT, xcol hoist)
// A/B'd: neutral-to-negative — reverted.
__global__ __launch_bounds__(256, 2)
void afm_kernel(const float* __restrict__ gnn, const float* __restrict__ xg,
                const float* __restrict__ Wg,  const float* __restrict__ bg,
                float* __restrict__ out)
{
  __shared__ __align__(16) _Float16 xh[2][FN * XS];     // 17.9 KB
  __shared__ __align__(16) float attn2d[2][FN * TS];    // 9.5 KB
  __shared__ __align__(16) float sp[2][4][PN];          // 16.9 KB [bi][group][p]
  __shared__ unsigned short rowcol[PN];                 // 1 KB
  __shared__ float rmax[2][8], rsum[2][4];

  const int tid  = threadIdx.x;
  const int b0   = blockIdx.x * 2;
  const int b1   = b0 + 1;
  const int wave = tid >> 6;
  const int lane = tid & 63;
  const int q    = lane >> 4;   // quad 0..3
  const int u    = lane & 15;
  const int nh   = wave & 1;    // n-half: cols [nh*64, nh*64+64)
  const int mh   = wave >> 1;   // m-half: tiles [0,17) / [17,33)

  // -------- x loads for BOTH batches issued first ---------------------------
  f32x4 xv0[4], xv1[4];
  f32x4 xt0 = {0,0,0,0}, xt1 = {0,0,0,0};
  XLOAD(xv0, xt0, b0);
  XLOAD(xv1, xt1, b1);

  // gnn passthrough value for EPIBOTH (thread (bi,d) = (tid>>7, tid&127))
  const float gpass = gnn[(size_t)(b0 + (tid >> 7)) * AN + (tid & 127)];

  // -------- W quadrant -> Bf regs; per-lane bias/gnn vectors ----------------
  // Bf[nn][kk]: lane holds W[a = nh*64+nn*16+u][k = kk*32+q*8 .. +8]
  // bq/gq[nn]: lane holds {bias,gnn}[a = nh*64+nn*16+q*4 .. +4] (fm^T layout)
  half8 Bf[4][4];
  f32x4 bq[4], g0q[4], g1q[4];
  #pragma unroll
  for (int nn = 0; nn < 4; nn++) {
    const int a = nh * 64 + nn * 16 + u;
    const float* src = Wg + (size_t)a * DN + q * 8;
    #pragma unroll
    for (int kk = 0; kk < 4; kk++) {
      f32x4 w0 = *(const f32x4*)(src + kk * 32);
      f32x4 w1 = *(const f32x4*)(src + kk * 32 + 4);
      u32x4 pk;
      pk.x = pkrtz(w0.x, w0.y);
      pk.y = pkrtz(w0.z, w0.w);
      pk.z = pkrtz(w1.x, w1.y);
      pk.w = pkrtz(w1.z, w1.w);
      Bf[nn][kk] = __builtin_bit_cast(half8, pk);
      asm volatile("" : "+v"(Bf[nn][kk]));   // pin: forbid remat/sinking
    }
    const int abase = nh * 64 + nn * 16 + q * 4;
    bq[nn]  = *(const f32x4*)&bg[abase];
    g0q[nn] = *(const f32x4*)&gnn[(size_t)b0 * AN + abase];
    g1q[nn] = *(const f32x4*)&gnn[(size_t)b1 * AN + abase];
    asm volatile("" : "+v"(bq[nn]), "+v"(g0q[nn]), "+v"(g1q[nn]));
  }

  // -------- VALU-only staging overlapped with load flight -------------------
  {
    float* a2z = &attn2d[0][0];
    for (int idx = tid; idx < 2 * FN * TS; idx += 256) a2z[idx] = 0.0f;
    for (int p = tid; p < PN; p += 256) {
      int i = 0, rem = p;
      while (rem >= FN - 1 - i) { rem -= FN - 1 - i; i++; }
      rowcol[p] = (unsigned short)(i | ((i + 1 + rem) << 8));
    }
  }
  XSTORE(xv0, xt0, 0);
  XSTORE(xv1, xt1, 1);
  __syncthreads();                                      // B1

  // -------- phase 1: interleaved walk over b0 AND b1 ------------------------
  {
    const int t_beg = mh ? 17 : 0;
    const int t_end = mh ? 33 : 17;
    float wm0 = -3.4e38f, wm1 = -3.4e38f;
    unsigned int rc_next = rowcol[t_beg * 16 + u];
    for (int t = t_beg; t < t_end; ++t) {
      const unsigned int rc = rc_next;
      if (t + 1 < t_end) rc_next = rowcol[(t + 1) * 16 + u];
      const int off_r = (rc & 255) * XS + q * 8;     // shared by both batches
      const int off_c = (rc >> 8) * XS + q * 8;

      f32x4 a0[4], a1[4];
      #pragma unroll
      for (int nn = 0; nn < 4; nn++) { a0[nn] = bq[nn]; a1[nn] = bq[nn]; }

      __builtin_amdgcn_s_setprio(1);
      #pragma unroll
      for (int kk = 0; kk < 4; kk++) {
        half8 af0 = *(const half8*)&xh[0][off_r + kk * 32] *
                    *(const half8*)&xh[0][off_c + kk * 32];
        half8 af1 = *(const half8*)&xh[1][off_r + kk * 32] *
                    *(const half8*)&xh[1][off_c + kk * 32];
        #pragma unroll
        for (int nn = 0; nn < 4; nn++) {
          a0[nn] = __builtin_amdgcn_mfma_f32_16x16x32_f16(Bf[nn][kk], af0, a0[nn], 0, 0, 0);
          a1[nn] = __builtin_amdgcn_mfma_f32_16x16x32_f16(Bf[nn][kk], af1, a1[nn], 0, 0, 0);
        }
      }
      __builtin_amdgcn_s_setprio(0);

      float s0, s1;
      RELUDOT(a0, g0q, s0);
      RELUDOT(a1, g1q, s1);
      s0 += __shfl_xor(s0, 16, 64);      // two independent bperms: pipelined
      s1 += __shfl_xor(s1, 16, 64);
      wm0 = fmaxf(wm0, s0);
      wm1 = fmaxf(wm1, s1);
      if ((q & 1) == 0) {
        const int gidx = (nh * 2 + (q >> 1)) * PN + t * 16 + u;
        (&sp[0][0][0])[gidx] = s0;
        (&sp[1][0][0])[gidx] = s1;
      }
    }
    wm0 = row_max16(wm0);
    wm1 = row_max16(wm1);
    if (lane == 0)  { rmax[0][wave * 2]     = wm0; rmax[1][wave * 2]     = wm1; }
    if (lane == 32) { rmax[0][wave * 2 + 1] = wm0; rmax[1][wave * 2 + 1] = wm1; }
  }
  __syncthreads();                                      // B2

  // -------- phase 2: SPH(b0) + SPH(b1), independent (ILP=2) -----------------
  SPH(0);
  SPH(1);
  __syncthreads();                                      // B3

  // -------- phase 3: EPIBOTH — thread (bi,d) computes batch bi, col d -------
  {
    const int bi = tid >> 7;          // wave-uniform (waves 0,1 -> b0; 2,3 -> b1)
    const int d  = tid & 127;
    const _Float16* xhb = &xh[bi][0];
    const float* a2 = &attn2d[bi][0];
    const float Zb = (rsum[bi][0] + rsum[bi][1]) + (rsum[bi][2] + rsum[bi][3]);

    float xcol[36];
    #pragma unroll
    for (int i = 0; i < FN; i++) xcol[i] = (float)xhb[i * XS + d];
    xcol[33] = 0.f; xcol[34] = 0.f; xcol[35] = 0.f;

    float acc0 = 0.f, acc1 = 0.f;     // i-parity split accumulators (ILP)
    #pragma unroll
    for (int i = 0; i < 32; i++) {
      const int L = FN - 1 - i;                  // pairs (i, i+1+jj), jj < L
      const int nf4 = (L + 3) >> 2;
      float ti = 0.f;
      #pragma unroll
      for (int t = 0; t < nf4; t++) {
        f32x4 a4 = *(const f32x4*)&a2[i * TS + t * 4];  // pad entries are 0
        ti = fmaf(a4.x, xcol[i + 1 + t * 4 + 0], ti);
        ti = fmaf(a4.y, xcol[i + 1 + t * 4 + 1], ti);
        ti = fmaf(a4.z, xcol[i + 1 + t * 4 + 2], ti);
        ti = fmaf(a4.w, xcol[i + 1 + t * 4 + 3], ti);
      }
      if (i & 1) acc1 = fmaf(xcol[i], ti, acc1);
      else       acc0 = fmaf(xcol[i], ti, acc0);
    }
    const size_t obase = (size_t)(b0 + bi) * (AN + DN);
    out[obase + AN + d] = (acc0 + acc1) * (100.0f / Zb);
    out[obase + d] = gpass;
  }
}

extern "C" void kernel_launch(void* const* d_in, const int* in_sizes, int n_in,
                              void* d_out, int out_size, void* d_ws, size_t ws_size,
                              hipStream_t stream) {
  (void)n_in; (void)out_size; (void)d_ws; (void)ws_size;
  const float* gnn  = (const float*)d_in[0];
  const float* x    = (const float*)d_in[1];
  const float* W    = (const float*)d_in[2];
  const float* bias = (const float*)d_in[3];
  float* out = (float*)d_out;
  const int Bn = in_sizes[0] / AN;   // 1024
  afm_kernel<<<dim3(Bn / 2), dim3(256), 0, stream>>>(gnn, x, W, bias, out);
}